// Round 2
// baseline (1063.727 us; speedup 1.0000x reference)
//
#include <hip/hip_runtime.h>
#include <hip/hip_bf16.h>

#define B_ 2
#define S_ 2048
#define D_ 2048
#define H_ 16
#define HD_ 128

typedef short s16x8 __attribute__((ext_vector_type(8)));
typedef float f32x4 __attribute__((ext_vector_type(4)));

__device__ inline unsigned short f2bf(float f) {
    __hip_bfloat16 h = __float2bfloat16(f);
    return __builtin_bit_cast(unsigned short, h);
}
__device__ inline float bf2f(unsigned short u) {
    __hip_bfloat16 h = __builtin_bit_cast(__hip_bfloat16, u);
    return __bfloat162float(h);
}

// ---------------- RoPE tables: cos/sin [S][64] fp32 ----------------
__global__ void rope_tab_k(float* __restrict__ cost, float* __restrict__ sint) {
    int s = blockIdx.x;
    int i = threadIdx.x;  // 0..63
    float inv = powf(10000.0f, -((float)(2 * i) / 128.0f));
    float ang = (float)s * inv;
    cost[s * 64 + i] = cosf(ang);
    sint[s * 64 + i] = sinf(ang);
}

// ---------------- GEMM: C[M][N] = A[M][K] * W[K][N] ----------------
// A is fp32 or bf16 (raw ushort); W is fp32 row-major (NOT transposed);
// C written bf16 or fp32. 128x128 tile, BK=64, 256 threads (4 waves 2x2).
template <bool A_BF16, bool OUT_BF16>
__global__ __launch_bounds__(256) void gemm_k(const void* __restrict__ Ap,
                                              const float* __restrict__ Bw,
                                              void* __restrict__ Cp,
                                              int M, int N, int K) {
    __shared__ unsigned short As[128][72];  // [m][k], pad to 72 (144B rows)
    __shared__ unsigned short Bs[128][72];  // [n][k] (transposed stage)
    int mbase = blockIdx.y * 128;
    int nbase = blockIdx.x * 128;
    int t = threadIdx.x;
    int w = t >> 6, lane = t & 63;
    int wr = w >> 1, wc = w & 1;
    int lr = lane >> 4, lc = lane & 15;

    f32x4 acc[4][4];
#pragma unroll
    for (int m = 0; m < 4; m++)
#pragma unroll
        for (int n = 0; n < 4; n++) acc[m][n] = f32x4{0.f, 0.f, 0.f, 0.f};

    for (int kb = 0; kb < K; kb += 64) {
        // ---- stage A tile [128][64] ----
        {
            int row = t >> 1;
            int kh = (t & 1) * 32;
            if constexpr (A_BF16) {
                const unsigned short* A =
                    (const unsigned short*)Ap + (size_t)(mbase + row) * K + kb + kh;
#pragma unroll
                for (int q = 0; q < 4; q++) {
                    s16x8 v = *(const s16x8*)(A + q * 8);
                    *(s16x8*)&As[row][kh + q * 8] = v;
                }
            } else {
                const float* A = (const float*)Ap + (size_t)(mbase + row) * K + kb + kh;
#pragma unroll
                for (int q = 0; q < 8; q++) {
                    float4 v = *(const float4*)(A + q * 4);
                    ushort4 o;
                    o.x = f2bf(v.x); o.y = f2bf(v.y); o.z = f2bf(v.z); o.w = f2bf(v.w);
                    *(ushort4*)&As[row][kh + q * 4] = o;
                }
            }
        }
        // ---- stage B tile with transpose: Bs[n][k] = W[kb+k][nbase+n] ----
        {
            int kk = t >> 2;           // 0..63
            int n0 = (t & 3) * 32;     // 0,32,64,96
            const float* Bp2 = Bw + (size_t)(kb + kk) * N + nbase + n0;
#pragma unroll
            for (int q = 0; q < 8; q++) {
                float4 v = *(const float4*)(Bp2 + q * 4);
                Bs[n0 + q * 4 + 0][kk] = f2bf(v.x);
                Bs[n0 + q * 4 + 1][kk] = f2bf(v.y);
                Bs[n0 + q * 4 + 2][kk] = f2bf(v.z);
                Bs[n0 + q * 4 + 3][kk] = f2bf(v.w);
            }
        }
        __syncthreads();
        // ---- compute ----
#pragma unroll
        for (int kc = 0; kc < 2; kc++) {
            int ko = kc * 32 + lr * 8;
            s16x8 af[4], bfr[4];
#pragma unroll
            for (int m = 0; m < 4; m++)
                af[m] = *(const s16x8*)&As[wr * 64 + m * 16 + lc][ko];
#pragma unroll
            for (int n = 0; n < 4; n++)
                bfr[n] = *(const s16x8*)&Bs[wc * 64 + n * 16 + lc][ko];
#pragma unroll
            for (int m = 0; m < 4; m++)
#pragma unroll
                for (int n = 0; n < 4; n++)
                    acc[m][n] = __builtin_amdgcn_mfma_f32_16x16x32_bf16(
                        af[m], bfr[n], acc[m][n], 0, 0, 0);
        }
        __syncthreads();
    }
    // ---- epilogue ----
    int rbase = mbase + wr * 64;
    int cbase = nbase + wc * 64;
#pragma unroll
    for (int m = 0; m < 4; m++)
#pragma unroll
        for (int n = 0; n < 4; n++)
#pragma unroll
            for (int r = 0; r < 4; r++) {
                int row = rbase + m * 16 + lr * 4 + r;
                int col = cbase + n * 16 + lc;
                float v = acc[m][n][r];
                if constexpr (OUT_BF16)
                    ((unsigned short*)Cp)[(size_t)row * N + col] = f2bf(v);
                else
                    ((float*)Cp)[(size_t)row * N + col] = v;
            }
}

// ---------------- RoPE + reshape to [B,H,S,HD] for Q and K ----------------
__global__ void rope_qk_k(const unsigned short* __restrict__ qtmp,
                          const unsigned short* __restrict__ ktmp,
                          const float* __restrict__ cost, const float* __restrict__ sint,
                          const int* __restrict__ pos_ids,
                          unsigned short* __restrict__ Qr, unsigned short* __restrict__ Kr) {
    int s = blockIdx.x;
    int bh = blockIdx.y;
    int b = bh >> 4, h = bh & 15;
    int d = threadIdx.x;  // 0..63
    int pos = pos_ids[(size_t)b * S_ + s];
    float c = cost[pos * 64 + d];
    float sn = sint[pos * 64 + d];
    size_t src = ((size_t)(b * S_ + s)) * D_ + h * HD_ + d;
    float q1 = bf2f(qtmp[src]), q2 = bf2f(qtmp[src + 64]);
    float k1 = bf2f(ktmp[src]), k2 = bf2f(ktmp[src + 64]);
    size_t dst = ((size_t)bh * S_ + s) * HD_ + d;
    Qr[dst] = f2bf(q1 * c - q2 * sn);
    Qr[dst + 64] = f2bf(q2 * c + q1 * sn);
    Kr[dst] = f2bf(k1 * c - k2 * sn);
    Kr[dst + 64] = f2bf(k2 * c + k1 * sn);
}

// ---------------- V transpose: Vt[B,H,HD,S] = V[B,S,H,HD] ----------------
__global__ __launch_bounds__(256) void vtrans_k(const unsigned short* __restrict__ vtmp,
                                                unsigned short* __restrict__ Vt) {
    __shared__ unsigned short tile[64][65];
    int sb = blockIdx.x * 64;
    int db = blockIdx.y * 64;  // 0 or 64
    int bh = blockIdx.z;
    int b = bh >> 4, h = bh & 15;
    int t = threadIdx.x;
    int c = t & 63, r4 = t >> 6;
#pragma unroll
    for (int i = 0; i < 16; i++) {
        int r = r4 * 16 + i;
        tile[r][c] = vtmp[((size_t)(b * S_ + sb + r)) * D_ + h * HD_ + db + c];
    }
    __syncthreads();
#pragma unroll
    for (int i = 0; i < 16; i++) {
        int dr = r4 * 16 + i;
        Vt[((size_t)bh * HD_ + db + dr) * S_ + sb + c] = tile[c][dr];
    }
}

// ---------------- Flash attention (causal), 1 wave per 16 q-rows ----------------
__global__ __launch_bounds__(64) void attn_k(const unsigned short* __restrict__ Qr,
                                             const unsigned short* __restrict__ Kr,
                                             const unsigned short* __restrict__ Vt,
                                             unsigned short* __restrict__ attnout) {
    __shared__ unsigned short P[16][32];
    int qt = blockIdx.x;
    int bh = blockIdx.y;
    int b = bh >> 4, h = bh & 15;
    int qbase = qt * 16;
    int lane = threadIdx.x;
    int lr = lane >> 4, lc = lane & 15;
    const unsigned short* Qb = Qr + ((size_t)bh * S_ + qbase) * HD_;
    const unsigned short* Kb = Kr + ((size_t)bh * S_) * HD_;
    const unsigned short* Vb = Vt + ((size_t)bh * HD_) * S_;

    s16x8 aq[4];
#pragma unroll
    for (int kc = 0; kc < 4; kc++)
        aq[kc] = *(const s16x8*)(Qb + (size_t)lc * HD_ + kc * 32 + lr * 8);

    float mrow[4], lsum[4];
    f32x4 o[8];
#pragma unroll
    for (int r = 0; r < 4; r++) { mrow[r] = -1e30f; lsum[r] = 0.f; }
#pragma unroll
    for (int dc = 0; dc < 8; dc++) o[dc] = f32x4{0.f, 0.f, 0.f, 0.f};

    int nkt = (qbase + 16 + 31) >> 5;
    const float scale = 0.088388347648318447f;  // 1/sqrt(128)

    for (int kt = 0; kt < nkt; kt++) {
        int kb = kt * 32;
        f32x4 sf[2];
#pragma unroll
        for (int ct = 0; ct < 2; ct++) {
            f32x4 s4 = f32x4{0.f, 0.f, 0.f, 0.f};
            const unsigned short* Kp = Kb + (size_t)(kb + ct * 16 + lc) * HD_ + lr * 8;
#pragma unroll
            for (int kc = 0; kc < 4; kc++) {
                s16x8 bk = *(const s16x8*)(Kp + kc * 32);
                s4 = __builtin_amdgcn_mfma_f32_16x16x32_bf16(aq[kc], bk, s4, 0, 0, 0);
            }
            sf[ct] = s4;
        }
        // scale + causal mask
#pragma unroll
        for (int ct = 0; ct < 2; ct++) {
            int key = kb + ct * 16 + lc;
#pragma unroll
            for (int r = 0; r < 4; r++) {
                int qr = qbase + lr * 4 + r;
                float v = sf[ct][r] * scale;
                sf[ct][r] = (key <= qr) ? v : -1e30f;
            }
        }
        // row max across the 16 lanes of each row-group
        float tmax[4];
#pragma unroll
        for (int r = 0; r < 4; r++) tmax[r] = fmaxf(sf[0][r], sf[1][r]);
#pragma unroll
        for (int off = 1; off < 16; off <<= 1)
#pragma unroll
            for (int r = 0; r < 4; r++)
                tmax[r] = fmaxf(tmax[r], __shfl_xor(tmax[r], off, 64));
        float alpha[4];
#pragma unroll
        for (int r = 0; r < 4; r++) {
            float nm = fmaxf(mrow[r], tmax[r]);
            alpha[r] = __expf(mrow[r] - nm);
            mrow[r] = nm;
        }
        float psum[4] = {0.f, 0.f, 0.f, 0.f};
#pragma unroll
        for (int ct = 0; ct < 2; ct++)
#pragma unroll
            for (int r = 0; r < 4; r++) {
                float p = __expf(sf[ct][r] - mrow[r]);
                sf[ct][r] = p;
                psum[r] += p;
            }
#pragma unroll
        for (int off = 1; off < 16; off <<= 1)
#pragma unroll
            for (int r = 0; r < 4; r++) psum[r] += __shfl_xor(psum[r], off, 64);
#pragma unroll
        for (int r = 0; r < 4; r++) lsum[r] = lsum[r] * alpha[r] + psum[r];
#pragma unroll
        for (int dc = 0; dc < 8; dc++)
#pragma unroll
            for (int r = 0; r < 4; r++) o[dc][r] *= alpha[r];
        // P (D-layout) -> LDS -> A-frag layout
        __syncthreads();
#pragma unroll
        for (int ct = 0; ct < 2; ct++)
#pragma unroll
            for (int r = 0; r < 4; r++) P[lr * 4 + r][ct * 16 + lc] = f2bf(sf[ct][r]);
        __syncthreads();
        s16x8 pa = *(const s16x8*)&P[lc][lr * 8];
        // PV: o[dc] += P(16x32) * V(32x16 per d-chunk)
#pragma unroll
        for (int dc = 0; dc < 8; dc++) {
            const unsigned short* Vp = Vb + (size_t)(dc * 16 + lc) * S_ + kb + lr * 8;
            s16x8 bv = *(const s16x8*)Vp;
            o[dc] = __builtin_amdgcn_mfma_f32_16x16x32_bf16(pa, bv, o[dc], 0, 0, 0);
        }
    }
    // epilogue: attnout[b*S+row][h*HD+col] bf16
#pragma unroll
    for (int dc = 0; dc < 8; dc++)
#pragma unroll
        for (int r = 0; r < 4; r++) {
            int row = qbase + lr * 4 + r;
            int col = h * HD_ + dc * 16 + lc;
            float v = o[dc][r] / lsum[r];
            attnout[((size_t)(b * S_ + row)) * D_ + col] = f2bf(v);
        }
}

extern "C" void kernel_launch(void* const* d_in, const int* in_sizes, int n_in,
                              void* d_out, int out_size, void* d_ws, size_t ws_size,
                              hipStream_t stream) {
    const float* hidden = (const float*)d_in[0];
    // d_in[1]: attention_mask (pure causal; implemented analytically)
    const int* pos_ids = (const int*)d_in[2];  // integer inputs arrive as int32
    const float* Wq = (const float*)d_in[3];
    const float* Wk = (const float*)d_in[4];
    const float* Wv = (const float*)d_in[5];
    const float* Wo = (const float*)d_in[6];
    float* out = (float*)d_out;

    char* ws = (char*)d_ws;
    const size_t MK = (size_t)B_ * S_ * D_;  // 8M elements
    float* cost = (float*)ws;                            // 512KB
    float* sint = (float*)(ws + 524288);                 // 512KB
    unsigned short* qtmp = (unsigned short*)(ws + 1048576);
    unsigned short* ktmp = qtmp + MK;
    unsigned short* vtmp = ktmp + MK;
    unsigned short* Qr = vtmp + MK;
    unsigned short* Kr = Qr + MK;
    unsigned short* Vt = Kr + MK;
    unsigned short* attnout = qtmp;  // reuse (qtmp dead after rope_qk_k)

    const int M = B_ * S_;  // 4096
    dim3 ggrid(D_ / 128, M / 128);  // (16, 32)

    rope_tab_k<<<S_, 64, 0, stream>>>(cost, sint);
    gemm_k<false, true><<<ggrid, 256, 0, stream>>>(hidden, Wq, qtmp, M, D_, D_);
    gemm_k<false, true><<<ggrid, 256, 0, stream>>>(hidden, Wk, ktmp, M, D_, D_);
    gemm_k<false, true><<<ggrid, 256, 0, stream>>>(hidden, Wv, vtmp, M, D_, D_);
    rope_qk_k<<<dim3(S_, B_ * H_), 64, 0, stream>>>(qtmp, ktmp, cost, sint, pos_ids, Qr, Kr);
    vtrans_k<<<dim3(S_ / 64, HD_ / 64, B_ * H_), 256, 0, stream>>>(vtmp, Vt);
    attn_k<<<dim3(S_ / 16, B_ * H_), 64, 0, stream>>>(Qr, Kr, Vt, attnout);
    gemm_k<true, false><<<ggrid, 256, 0, stream>>>(attnout, Wo, out, M, D_, D_);
}